// Round 4
// baseline (254.956 us; speedup 1.0000x reference)
//
#include <hip/hip_runtime.h>

typedef unsigned short u16;
typedef __attribute__((ext_vector_type(8))) short bf16x8;
typedef __attribute__((ext_vector_type(4))) short bf16x4;
typedef __attribute__((ext_vector_type(4))) float f32x4;
typedef __attribute__((ext_vector_type(4))) unsigned short u16x4;

#define AS1 __attribute__((address_space(1)))
#define AS3 __attribute__((address_space(3)))

// ---- bf16 helpers (raw u16 storage) ----
__device__ __forceinline__ float b2f(u16 s) {
    return __uint_as_float(((unsigned)s) << 16);
}
__device__ __forceinline__ u16 f2b(float f) {
    unsigned u = __float_as_uint(f);
    unsigned r = 0x7fffu + ((u >> 16) & 1u);
    return (u16)((u + r) >> 16);
}

// async global->LDS, 16B per lane
__device__ __forceinline__ void g2l16(const u16* g, u16* l) {
    __builtin_amdgcn_global_load_lds((const AS1 void*)g, (AS3 void*)l, 16, 0, 0);
}

// raw hardware exp2
#if __has_builtin(__builtin_amdgcn_exp2f)
#define EXP2(x) __builtin_amdgcn_exp2f(x)
#else
#define EXP2(x) exp2f(x)
#endif

// K=16 PV MFMA: native 16x16x16 bf16 if the builtin exists, else zero-padded K=32.
#if __has_builtin(__builtin_amdgcn_mfma_f32_16x16x16bf16_1k)
__device__ __forceinline__ f32x4 pvmfma(bf16x4 a, bf16x4 b, f32x4 c) {
    return __builtin_amdgcn_mfma_f32_16x16x16bf16_1k(a, b, c, 0, 0, 0);
}
#else
__device__ __forceinline__ f32x4 pvmfma(bf16x4 a4, bf16x4 b4, f32x4 c) {
    bf16x8 a = {a4.x, a4.y, a4.z, a4.w, 0, 0, 0, 0};
    bf16x8 b = {b4.x, b4.y, b4.z, b4.w, 0, 0, 0, 0};
    return __builtin_amdgcn_mfma_f32_16x16x32_bf16(a, b, c, 0, 0, 0);
}
#endif

// ---------------------------------------------------------------------------
// Kernel 0: fp32 -> bf16 cast
// ---------------------------------------------------------------------------
__global__ __launch_bounds__(256) void cast_f32_bf16(
    const float* __restrict__ s, u16* __restrict__ d, int n4)
{
    const int i = blockIdx.x * 256 + threadIdx.x;
    if (i < n4) {
        const float4 v = ((const float4*)s)[i];
        u16x4 o;
        o.x = f2b(v.x); o.y = f2b(v.y); o.z = f2b(v.z); o.w = f2b(v.w);
        ((u16x4*)d)[i] = o;
    }
}

// ---------------------------------------------------------------------------
// Kernel 1: build combined projection matrices Mt[2304][768] (B^T layout), bf16.
// Q gets 0.125*log2(e) folded in (flash uses exp2). 8 output rows per block.
// ---------------------------------------------------------------------------
__global__ __launch_bounds__(256) void build_M(
    const float* __restrict__ Wq0, const float* __restrict__ Wq1, const float* __restrict__ Wq2,
    const float* __restrict__ Wk0, const float* __restrict__ Wk1, const float* __restrict__ Wk2,
    const float* __restrict__ Wv0, const float* __restrict__ Wv1, const float* __restrict__ Wv2,
    u16* __restrict__ Mt)
{
    const int bx = blockIdx.x;            // 0..287
    const int which = bx / 96;            // 0=Q,1=K,2=V
    const int mmBase = (bx - which * 96) * 8;
    const float* W0 = (which == 0) ? Wq0 : (which == 1) ? Wk0 : Wv0;
    const float* W1 = (which == 0) ? Wq1 : (which == 1) ? Wk1 : Wv1;
    const float* W2 = (which == 0) ? Wq2 : (which == 1) ? Wk2 : Wv2;
    const float scale = (which == 0) ? 0.125f * 1.4426950408889634f : 1.0f;

    __shared__ float w0s[8][64];
    __shared__ float w1s[12 * 65];
    __shared__ float w2s[64 * 65];

    const int t = threadIdx.x;
    for (int i = t; i < 512; i += 256) {
        const int row = i >> 6, r = i & 63;
        w0s[row][r] = W0[(mmBase + row) * 64 + r] * scale;
    }
    for (int i = t; i < 768; i += 256)  w1s[(i >> 6) * 65 + (i & 63)] = W1[i];
    for (int i = t; i < 4096; i += 256) w2s[(i >> 6) * 65 + (i & 63)] = W2[i];
    __syncthreads();

    for (int m8 = 0; m8 < 8; ++m8) {
        for (int c = t; c < 768; c += 256) {
            const int nh = c >> 6, dd = c & 63;
            float s = 0.f;
#pragma unroll
            for (int r = 0; r < 64; ++r)
                s += w0s[m8][r] * w1s[nh * 65 + r] * w2s[dd * 65 + r];
            Mt[(size_t)(which * 768 + mmBase + m8) * 768 + c] = f2b(s);
        }
    }
}

// ---------------------------------------------------------------------------
// Kernel 2/4: 128x128 MFMA GEMM, K=768, A[M,768] x Bt[N,768], bf16 in.
// MODE 0: scatter bf16 C into q,k [bh][l][d]; V stored TRANSPOSED vt[bh][d][l].
// MODE 1: +fp32 bias, write fp32 [8192,768].
// ---------------------------------------------------------------------------
template <int MODE>
__global__ __launch_bounds__(256, 2) void gemm_bt(
    const u16* __restrict__ A, const u16* __restrict__ Bt,
    void* __restrict__ Cv, const float* __restrict__ bias)
{
    __shared__ u16 As[128 * 32];
    __shared__ u16 Bs[128 * 32];

    const int tid  = threadIdx.x;
    const int lane = tid & 63, wv = tid >> 6;
    const int l15  = lane & 15, quad = lane >> 4;
    const int rowBase = blockIdx.y * 128;
    const int colBase = blockIdx.x * 128;

    const int srow = wv * 32 + (lane >> 2);
    const int scol = (lane & 3) * 8;
    const u16* aSrc = A  + (size_t)(rowBase + srow) * 768 + scol;
    const u16* bSrc = Bt + (size_t)(colBase + srow) * 768 + scol;
    u16* aDst = As + wv * 1024;
    u16* bDst = Bs + wv * 1024;

    const f32x4 zero4 = {0.f, 0.f, 0.f, 0.f};
    f32x4 acc[4][4];
#pragma unroll
    for (int tm = 0; tm < 4; ++tm)
#pragma unroll
        for (int tn = 0; tn < 4; ++tn) acc[tm][tn] = zero4;

    const int wr = (wv >> 1) * 64, wc = (wv & 1) * 64;

    for (int kk = 0; kk < 768; kk += 32) {
        __syncthreads();
        g2l16(aSrc + kk,            aDst);
        g2l16(aSrc + kk + 16 * 768, aDst + 512);
        g2l16(bSrc + kk,            bDst);
        g2l16(bSrc + kk + 16 * 768, bDst + 512);
        __syncthreads();

        bf16x8 af[4], bfm[4];
#pragma unroll
        for (int t = 0; t < 4; ++t) {
            af[t]  = *(const bf16x8*)(As + (wr + t * 16 + l15) * 32 + quad * 8);
            bfm[t] = *(const bf16x8*)(Bs + (wc + t * 16 + l15) * 32 + quad * 8);
        }
#pragma unroll
        for (int tm = 0; tm < 4; ++tm)
#pragma unroll
            for (int tn = 0; tn < 4; ++tn)
                acc[tm][tn] = __builtin_amdgcn_mfma_f32_16x16x32_bf16(
                    af[tm], bfm[tn], acc[tm][tn], 0, 0, 0);
    }

    if (MODE == 0) {
        u16* outp0 = (u16*)Cv;
        const int which = colBase / 768;
        const int mmBase = colBase - which * 768 + wc;
        if (which < 2) {
            // q,k layout [bh][l][d]
            u16* outp = outp0 + (size_t)which * 6291456;
#pragma unroll
            for (int tm = 0; tm < 4; ++tm) {
                const int grow = rowBase + wr + tm * 16 + quad * 4;
                const int b = grow >> 10, l = grow & 1023;
#pragma unroll
                for (int tn = 0; tn < 4; ++tn) {
                    const int mmv = mmBase + tn * 16 + l15;
                    const int h = mmv >> 6, d = mmv & 63;
                    const size_t base = (((size_t)(b * 12 + h) * 1024 + l) << 6) + d;
#pragma unroll
                    for (int r = 0; r < 4; ++r)
                        outp[base + (size_t)r * 64] = f2b(acc[tm][tn][r]);
                }
            }
        } else {
            // V stored transposed: vt[bh][d][l]; r-values contiguous in l -> 8B packed store
            u16* outp = outp0 + (size_t)2 * 6291456;
#pragma unroll
            for (int tm = 0; tm < 4; ++tm) {
                const int grow = rowBase + wr + tm * 16 + quad * 4;
                const int b = grow >> 10, l = grow & 1023;
#pragma unroll
                for (int tn = 0; tn < 4; ++tn) {
                    const int mmv = mmBase + tn * 16 + l15;
                    const int h = mmv >> 6, d = mmv & 63;
                    u16x4 pk;
                    pk.x = f2b(acc[tm][tn][0]); pk.y = f2b(acc[tm][tn][1]);
                    pk.z = f2b(acc[tm][tn][2]); pk.w = f2b(acc[tm][tn][3]);
                    *(u16x4*)(outp + (((size_t)(b * 12 + h) * 64 + d) << 10) + l) = pk;
                }
            }
        }
    } else {
        float* C = (float*)Cv;
#pragma unroll
        for (int tm = 0; tm < 4; ++tm) {
            const int grow = rowBase + wr + tm * 16 + quad * 4;
#pragma unroll
            for (int tn = 0; tn < 4; ++tn) {
                const int gcol = colBase + wc + tn * 16 + l15;
                const float bv = bias[gcol];
#pragma unroll
                for (int r = 0; r < 4; ++r)
                    C[(size_t)(grow + r) * 768 + gcol] = acc[tm][tn][r] + bv;
            }
        }
    }
}

// ---------------------------------------------------------------------------
// Kernel 3: flash attention v3.
// Grid (16, 96): block = 64 q rows of one (b,h), 4 waves, 16 q rows/wave.
// Q fragments live in registers (loaded straight from global, no Q LDS).
// S^T = K*Q^T -> exp2 lands directly in PV A-operand layout. No max-subtraction
// (|S| < ~0.5 by construction; log2e folded into M_Q). Native K=16 PV MFMA.
// Next K/V tile register-prefetched across the barrier.
// ---------------------------------------------------------------------------
__global__ __launch_bounds__(256, 5) void flash_attn3(
    const u16* __restrict__ qkv, u16* __restrict__ o)
{
    const int qt = blockIdx.x;          // 0..15 (64 q rows each)
    const int bh = blockIdx.y;          // 0..95
    const int b = bh / 12, h = bh - b * 12;
    const u16* qp = qkv + (size_t)bh * 65536 + qt * 4096;
    const u16* kp = qkv + 6291456 + (size_t)bh * 65536;
    const u16* vp = qkv + 2 * 6291456 + (size_t)bh * 65536;   // vt [d][l]

    __shared__ u16 Ks[64][72];
    __shared__ u16 Vs[64][72];          // Vs[d][key]

    const int t = threadIdx.x;
    const int lane = t & 63, wv = t >> 6;
    const int l15 = lane & 15, quad = lane >> 4;

    // Q fragments: wave wv owns q rows [wv*16, wv*16+16); one coalesced 16B load each
    bf16x8 qf[2];
    qf[0] = *(const bf16x8*)(qp + (wv * 16 + l15) * 64 + quad * 8);
    qf[1] = *(const bf16x8*)(qp + (wv * 16 + l15) * 64 + 32 + quad * 8);

    const int srow = t >> 2;            // staging row 0..63
    const int scol = (t & 3) * 16;      // staging col (u16)

    // prefetch tile 0
    int4 kr0 = *(const int4*)(kp + srow * 64 + scol);
    int4 kr1 = *(const int4*)(kp + srow * 64 + scol + 8);
    int4 vr0 = *(const int4*)(vp + srow * 1024 + scol);
    int4 vr1 = *(const int4*)(vp + srow * 1024 + scol + 8);

    const f32x4 zero4 = {0.f, 0.f, 0.f, 0.f};
    f32x4 o_acc[4];
    float l_sum = 0.f;
#pragma unroll
    for (int tn = 0; tn < 4; ++tn) o_acc[tn] = zero4;

    for (int kt = 0; kt < 16; ++kt) {
        __syncthreads();                 // prior-iter Ks/Vs consumers done
        *(int4*)&Ks[srow][scol]     = kr0;
        *(int4*)&Ks[srow][scol + 8] = kr1;
        *(int4*)&Vs[srow][scol]     = vr0;
        *(int4*)&Vs[srow][scol + 8] = vr1;
        __syncthreads();

        if (kt < 15) {                   // prefetch next tile (overlaps compute)
            kr0 = *(const int4*)(kp + (kt + 1) * 4096 + srow * 64 + scol);
            kr1 = *(const int4*)(kp + (kt + 1) * 4096 + srow * 64 + scol + 8);
            vr0 = *(const int4*)(vp + srow * 1024 + (kt + 1) * 64 + scol);
            vr1 = *(const int4*)(vp + srow * 1024 + (kt + 1) * 64 + scol + 8);
        }

        // S^T: D[key][q] = sum_d K[key][d] Q[q][d]. A=K-frag, B=Q-frag (registers).
        f32x4 Sacc[4];
#pragma unroll
        for (int tk = 0; tk < 4; ++tk) Sacc[tk] = zero4;
#pragma unroll
        for (int ks = 0; ks < 2; ++ks) {
#pragma unroll
            for (int tk = 0; tk < 4; ++tk) {
                const bf16x8 kf = *(const bf16x8*)&Ks[tk * 16 + l15][ks * 32 + quad * 8];
                Sacc[tk] = __builtin_amdgcn_mfma_f32_16x16x32_bf16(kf, qf[ks], Sacc[tk], 0, 0, 0);
            }
        }

        // P = exp2(S'): lane holds P[q=l15][key = tk*16+quad*4+r]
        bf16x4 pf[4];
#pragma unroll
        for (int tk = 0; tk < 4; ++tk) {
            const float p0 = EXP2(Sacc[tk][0]);
            const float p1 = EXP2(Sacc[tk][1]);
            const float p2 = EXP2(Sacc[tk][2]);
            const float p3 = EXP2(Sacc[tk][3]);
            l_sum += (p0 + p1) + (p2 + p3);
            bf16x4 pk;
            pk.x = (short)f2b(p0); pk.y = (short)f2b(p1);
            pk.z = (short)f2b(p2); pk.w = (short)f2b(p3);
            pf[tk] = pk;
        }

        // O += P V : A = pf (registers), B = Vs[d][key] b64 fragments
#pragma unroll
        for (int tk = 0; tk < 4; ++tk) {
#pragma unroll
            for (int tn = 0; tn < 4; ++tn) {
                const bf16x4 vf = *(const bf16x4*)&Vs[tn * 16 + l15][tk * 16 + quad * 4];
                o_acc[tn] = pvmfma(pf[tk], vf, o_acc[tn]);
            }
        }
    }

    // L: sum partials across quads (per q-row = l15)
    l_sum += __shfl_xor(l_sum, 16, 64);
    l_sum += __shfl_xor(l_sum, 32, 64);

    // epilogue: o_acc lane holds O[q_local = quad*4+r][d = tn*16+l15]
#pragma unroll
    for (int r = 0; r < 4; ++r) {
        const float Lv = __shfl(l_sum, quad * 4 + r, 64);
        const float inv = 1.0f / Lv;
        const int token = qt * 64 + wv * 16 + quad * 4 + r;
#pragma unroll
        for (int tn = 0; tn < 4; ++tn) {
            const int col = h * 64 + tn * 16 + l15;
            o[(size_t)(b * 1024 + token) * 768 + col] = f2b(o_acc[tn][r] * inv);
        }
    }
}

// ---------------------------------------------------------------------------
extern "C" void kernel_launch(void* const* d_in, const int* in_sizes, int n_in,
                              void* d_out, int out_size, void* d_ws, size_t ws_size,
                              hipStream_t stream)
{
    const float* x      = (const float*)d_in[0];
    const float* Wq0    = (const float*)d_in[1];
    const float* Wq1    = (const float*)d_in[2];
    const float* Wq2    = (const float*)d_in[3];
    const float* Wk0    = (const float*)d_in[4];
    const float* Wk1    = (const float*)d_in[5];
    const float* Wk2    = (const float*)d_in[6];
    const float* Wv0    = (const float*)d_in[7];
    const float* Wv1    = (const float*)d_in[8];
    const float* Wv2    = (const float*)d_in[9];
    const float* proj_w = (const float*)d_in[10];
    const float* proj_b = (const float*)d_in[11];
    float* outp = (float*)d_out;

    char* ws = (char*)d_ws;
    u16* Mt   = (u16*)ws;                              // 3,538,944 B
    u16* xb   = (u16*)(ws + 3538944);                  // 12,582,912 B
    u16* attn = xb;                                    // aliases xb (dead after gemm0)
    u16* qkv  = (u16*)(ws + 3538944 + 12582912);       // 37,748,736 B
    u16* pwb  = (u16*)(ws + 3538944 + 12582912 + 37748736); // 1,179,648 B

    cast_f32_bf16<<<6144, 256, 0, stream>>>(x, xb, 1572864);
    cast_f32_bf16<<<576, 256, 0, stream>>>(proj_w, pwb, 147456);
    build_M<<<288, 256, 0, stream>>>(Wq0, Wq1, Wq2, Wk0, Wk1, Wk2, Wv0, Wv1, Wv2, Mt);
    gemm_bt<0><<<dim3(18, 64), 256, 0, stream>>>(xb, Mt, qkv, nullptr);
    flash_attn3<<<dim3(16, 96), 256, 0, stream>>>(qkv, attn);
    gemm_bt<1><<<dim3(6, 64), 256, 0, stream>>>(attn, pwb, outp, proj_b);
}

// Round 5
// 192.927 us; speedup vs baseline: 1.3215x; 1.3215x over previous
//
#include <hip/hip_runtime.h>

typedef unsigned short u16;
typedef __attribute__((ext_vector_type(8))) short bf16x8;
typedef __attribute__((ext_vector_type(4))) float f32x4;
typedef __attribute__((ext_vector_type(4))) unsigned short u16x4;

#define AS1 __attribute__((address_space(1)))
#define AS3 __attribute__((address_space(3)))

__device__ __forceinline__ float b2f(u16 s) {
    return __uint_as_float(((unsigned)s) << 16);
}
__device__ __forceinline__ u16 f2b(float f) {
    unsigned u = __float_as_uint(f);
    unsigned r = 0x7fffu + ((u >> 16) & 1u);
    return (u16)((u + r) >> 16);
}

// async global->LDS, 16B per lane
__device__ __forceinline__ void g2l16(const u16* g, u16* l) {
    __builtin_amdgcn_global_load_lds((const AS1 void*)g, (AS3 void*)l, 16, 0, 0);
}

#if __has_builtin(__builtin_amdgcn_exp2f)
#define EXP2(x) __builtin_amdgcn_exp2f(x)
#else
#define EXP2(x) exp2f(x)
#endif

// ---------------------------------------------------------------------------
// Kernel 0: fp32 -> bf16 cast
// ---------------------------------------------------------------------------
__global__ __launch_bounds__(256) void cast_f32_bf16(
    const float* __restrict__ s, u16* __restrict__ d, int n4)
{
    const int i = blockIdx.x * 256 + threadIdx.x;
    if (i < n4) {
        const float4 v = ((const float4*)s)[i];
        u16x4 o;
        o.x = f2b(v.x); o.y = f2b(v.y); o.z = f2b(v.z); o.w = f2b(v.w);
        ((u16x4*)d)[i] = o;
    }
}

// ---------------------------------------------------------------------------
// Kernel 1: build small factored matrices (replaces build_M):
//   G[row = which*64 + r][c = h*64+d] = W1w[h,r] * W2w[d,r]        (192 x 768)
//   W0b[row = which*768 + mm][r]      = W0w[mm,r] * scale_which    (2304 x 64)
// scale_Q = 0.125 * log2(e)  (flash uses exp2)
// ---------------------------------------------------------------------------
__global__ __launch_bounds__(256) void build_small(
    const float* __restrict__ Wq0, const float* __restrict__ Wq1, const float* __restrict__ Wq2,
    const float* __restrict__ Wk0, const float* __restrict__ Wk1, const float* __restrict__ Wk2,
    const float* __restrict__ Wv0, const float* __restrict__ Wv1, const float* __restrict__ Wv2,
    u16* __restrict__ G, u16* __restrict__ W0b)
{
    const int idx = blockIdx.x * 256 + threadIdx.x;
    if (idx < 147456) {
        const int row = idx / 768, c = idx - row * 768;
        const int which = row >> 6, r = row & 63;
        const int h = c >> 6, d = c & 63;
        const float* W1 = (which == 0) ? Wq1 : (which == 1) ? Wk1 : Wv1;
        const float* W2 = (which == 0) ? Wq2 : (which == 1) ? Wk2 : Wv2;
        G[idx] = f2b(W1[h * 64 + r] * W2[d * 64 + r]);
    } else {
        const int j = idx - 147456;
        const int row = j >> 6, r = j & 63;
        const int which = row / 768, mm = row - which * 768;
        const float* W0 = (which == 0) ? Wq0 : (which == 1) ? Wk0 : Wv0;
        const float scale = (which == 0) ? 0.125f * 1.4426950408889634f : 1.0f;
        W0b[j] = f2b(W0[mm * 64 + r] * scale);
    }
}

// ---------------------------------------------------------------------------
// Kernel 2: t = x @ G^T-layout  (M=8192, N=192, K=768). 64x64 tiles, grid (3,128).
// ---------------------------------------------------------------------------
__global__ __launch_bounds__(256, 2) void gemm_t(
    const u16* __restrict__ A, const u16* __restrict__ G, u16* __restrict__ T)
{
    __shared__ u16 As[64 * 32];
    __shared__ u16 Bs[64 * 32];

    const int tid = threadIdx.x;
    const int lane = tid & 63, wv = tid >> 6;
    const int l15 = lane & 15, quad = lane >> 4;
    const int rowBase = blockIdx.y * 64;
    const int colBase = blockIdx.x * 64;

    const int srow = wv * 16 + (lane >> 2);     // 0..63
    const int scol = (lane & 3) * 8;
    const u16* aSrc = A + (size_t)(rowBase + srow) * 768 + scol;
    const u16* bSrc = G + (size_t)(colBase + srow) * 768 + scol;
    u16* aDst = As + wv * 512;
    u16* bDst = Bs + wv * 512;

    const f32x4 zero4 = {0.f, 0.f, 0.f, 0.f};
    f32x4 acc[4];
#pragma unroll
    for (int tn = 0; tn < 4; ++tn) acc[tn] = zero4;

    for (int kk = 0; kk < 768; kk += 32) {
        __syncthreads();
        g2l16(aSrc + kk, aDst);
        g2l16(bSrc + kk, bDst);
        __syncthreads();

        const bf16x8 af = *(const bf16x8*)(As + (wv * 16 + l15) * 32 + quad * 8);
#pragma unroll
        for (int tn = 0; tn < 4; ++tn) {
            const bf16x8 bf = *(const bf16x8*)(Bs + (tn * 16 + l15) * 32 + quad * 8);
            acc[tn] = __builtin_amdgcn_mfma_f32_16x16x32_bf16(af, bf, acc[tn], 0, 0, 0);
        }
    }

#pragma unroll
    for (int tn = 0; tn < 4; ++tn) {
        const int col = colBase + tn * 16 + l15;
#pragma unroll
        for (int r = 0; r < 4; ++r) {
            const int grow = rowBase + wv * 16 + quad * 4 + r;
            T[(size_t)grow * 192 + col] = f2b(acc[tn][r]);
        }
    }
}

// ---------------------------------------------------------------------------
// Kernel 3: qkv = t @ W0b^T  (K=64). 128x128 tiles, grid (18,64).
// Epilogue scatters q,k as [bh][l][d]; V stored TRANSPOSED vt[bh][d][l].
// ---------------------------------------------------------------------------
__global__ __launch_bounds__(256, 2) void gemm_expand(
    const u16* __restrict__ T, const u16* __restrict__ W0b, u16* __restrict__ qkvp)
{
    __shared__ u16 As[128 * 32];
    __shared__ u16 Bs[128 * 32];

    const int tid  = threadIdx.x;
    const int lane = tid & 63, wv = tid >> 6;
    const int l15  = lane & 15, quad = lane >> 4;
    const int rowBase = blockIdx.y * 128;
    const int colBase = blockIdx.x * 128;
    const int which = blockIdx.x / 6;           // 0=Q,1=K,2=V

    const int srow = wv * 32 + (lane >> 2);
    const int scol = (lane & 3) * 8;
    const u16* aSrc = T   + (size_t)(rowBase + srow) * 192 + which * 64 + scol;
    const u16* bSrc = W0b + (size_t)(colBase + srow) * 64 + scol;
    u16* aDst = As + wv * 1024;
    u16* bDst = Bs + wv * 1024;

    const f32x4 zero4 = {0.f, 0.f, 0.f, 0.f};
    f32x4 acc[4][4];
#pragma unroll
    for (int tm = 0; tm < 4; ++tm)
#pragma unroll
        for (int tn = 0; tn < 4; ++tn) acc[tm][tn] = zero4;

    const int wr = (wv >> 1) * 64, wc = (wv & 1) * 64;

    for (int kk = 0; kk < 64; kk += 32) {
        __syncthreads();
        g2l16(aSrc + kk,           aDst);
        g2l16(aSrc + kk + 16 * 192, aDst + 512);
        g2l16(bSrc + kk,           bDst);
        g2l16(bSrc + kk + 16 * 64,  bDst + 512);
        __syncthreads();

        bf16x8 af[4], bfm[4];
#pragma unroll
        for (int t = 0; t < 4; ++t) {
            af[t]  = *(const bf16x8*)(As + (wr + t * 16 + l15) * 32 + quad * 8);
            bfm[t] = *(const bf16x8*)(Bs + (wc + t * 16 + l15) * 32 + quad * 8);
        }
#pragma unroll
        for (int tm = 0; tm < 4; ++tm)
#pragma unroll
            for (int tn = 0; tn < 4; ++tn)
                acc[tm][tn] = __builtin_amdgcn_mfma_f32_16x16x32_bf16(
                    af[tm], bfm[tn], acc[tm][tn], 0, 0, 0);
    }

    const int mmBase = colBase - which * 768 + wc;
    if (which < 2) {
        u16* outp = qkvp + (size_t)which * 6291456;
#pragma unroll
        for (int tm = 0; tm < 4; ++tm) {
            const int grow = rowBase + wr + tm * 16 + quad * 4;
            const int b = grow >> 10, l = grow & 1023;
#pragma unroll
            for (int tn = 0; tn < 4; ++tn) {
                const int mmv = mmBase + tn * 16 + l15;
                const int h = mmv >> 6, d = mmv & 63;
                const size_t base = (((size_t)(b * 12 + h) * 1024 + l) << 6) + d;
#pragma unroll
                for (int r = 0; r < 4; ++r)
                    outp[base + (size_t)r * 64] = f2b(acc[tm][tn][r]);
            }
        }
    } else {
        u16* outp = qkvp + (size_t)2 * 6291456;
#pragma unroll
        for (int tm = 0; tm < 4; ++tm) {
            const int grow = rowBase + wr + tm * 16 + quad * 4;
            const int b = grow >> 10, l = grow & 1023;
#pragma unroll
            for (int tn = 0; tn < 4; ++tn) {
                const int mmv = mmBase + tn * 16 + l15;
                const int h = mmv >> 6, d = mmv & 63;
                u16x4 pk;
                pk.x = f2b(acc[tm][tn][0]); pk.y = f2b(acc[tm][tn][1]);
                pk.z = f2b(acc[tm][tn][2]); pk.w = f2b(acc[tm][tn][3]);
                *(u16x4*)(outp + (((size_t)(b * 12 + h) * 64 + d) << 10) + l) = pk;
            }
        }
    }
}

// ---------------------------------------------------------------------------
// Kernel 4: flash attention v4 — full-rate K=32 PV via permuted K staging.
// K LDS rows permuted: p5=(b4 b3 b2 b1 b0) -> row=(b2 b4 b3 b1 b0), so the two
// S^T tiles of a 32-key group exit with lane-quad holding keys quad*8+j, i.e.
// directly in K=32 A-operand layout; V stays in physical key order.
// ---------------------------------------------------------------------------
__global__ __launch_bounds__(256, 5) void flash_attn4(
    const u16* __restrict__ qkv, u16* __restrict__ o)
{
    const int qt = blockIdx.x;          // 0..15 (64 q rows each)
    const int bh = blockIdx.y;          // 0..95
    const int b = bh / 12, h = bh - b * 12;
    const u16* qp = qkv + (size_t)bh * 65536 + qt * 4096;
    const u16* kp = qkv + 6291456 + (size_t)bh * 65536;
    const u16* vp = qkv + 2 * 6291456 + (size_t)bh * 65536;   // vt [d][l]

    __shared__ u16 Ks[64][72];
    __shared__ u16 Vs[64][72];          // Vs[d][key]

    const int t = threadIdx.x;
    const int lane = t & 63, wv = t >> 6;
    const int l15 = lane & 15, quad = lane >> 4;

    // Q fragments in registers
    bf16x8 qf[2];
    qf[0] = *(const bf16x8*)(qp + (wv * 16 + l15) * 64 + quad * 8);
    qf[1] = *(const bf16x8*)(qp + (wv * 16 + l15) * 64 + 32 + quad * 8);

    const int srow = t >> 2;            // physical key / d row 0..63
    const int scol = (t & 3) * 16;
    const int p5 = srow & 31;
    const int lrow = (srow & 32) | ((p5 & 4) << 2) | ((p5 & 16) >> 1)
                   | ((p5 & 8) >> 1) | (p5 & 3);   // permuted K row

    // prefetch tile 0
    int4 kr0 = *(const int4*)(kp + srow * 64 + scol);
    int4 kr1 = *(const int4*)(kp + srow * 64 + scol + 8);
    int4 vr0 = *(const int4*)(vp + srow * 1024 + scol);
    int4 vr1 = *(const int4*)(vp + srow * 1024 + scol + 8);

    const f32x4 zero4 = {0.f, 0.f, 0.f, 0.f};
    f32x4 o_acc[4];
    float l_sum = 0.f;
#pragma unroll
    for (int tn = 0; tn < 4; ++tn) o_acc[tn] = zero4;

    for (int kt = 0; kt < 16; ++kt) {
        __syncthreads();
        *(int4*)&Ks[lrow][scol]     = kr0;
        *(int4*)&Ks[lrow][scol + 8] = kr1;
        *(int4*)&Vs[srow][scol]     = vr0;
        *(int4*)&Vs[srow][scol + 8] = vr1;
        __syncthreads();

        if (kt < 15) {
            kr0 = *(const int4*)(kp + (kt + 1) * 4096 + srow * 64 + scol);
            kr1 = *(const int4*)(kp + (kt + 1) * 4096 + srow * 64 + scol + 8);
            vr0 = *(const int4*)(vp + srow * 1024 + (kt + 1) * 64 + scol);
            vr1 = *(const int4*)(vp + srow * 1024 + (kt + 1) * 64 + scol + 8);
        }

        // S^T = K x Q^T (keys permuted per tile)
        f32x4 Sacc[4];
#pragma unroll
        for (int tk = 0; tk < 4; ++tk) Sacc[tk] = zero4;
#pragma unroll
        for (int ks = 0; ks < 2; ++ks) {
#pragma unroll
            for (int tk = 0; tk < 4; ++tk) {
                const bf16x8 kf = *(const bf16x8*)&Ks[tk * 16 + l15][ks * 32 + quad * 8];
                Sacc[tk] = __builtin_amdgcn_mfma_f32_16x16x32_bf16(kf, qf[ks], Sacc[tk], 0, 0, 0);
            }
        }

        // P = exp2(S'); pf8[g] is the K=32 A-fragment for key group g
        bf16x8 pf8[2] = {};
#pragma unroll
        for (int tk = 0; tk < 4; ++tk) {
            const int g = tk >> 1, hf = (tk & 1) * 4;
            const float p0 = EXP2(Sacc[tk][0]);
            const float p1 = EXP2(Sacc[tk][1]);
            const float p2 = EXP2(Sacc[tk][2]);
            const float p3 = EXP2(Sacc[tk][3]);
            l_sum += (p0 + p1) + (p2 + p3);
            pf8[g][hf + 0] = (short)f2b(p0);
            pf8[g][hf + 1] = (short)f2b(p1);
            pf8[g][hf + 2] = (short)f2b(p2);
            pf8[g][hf + 3] = (short)f2b(p3);
        }

        // O += P V : full-rate K=32 MFMAs, V read as b128 in physical key order
#pragma unroll
        for (int g = 0; g < 2; ++g) {
#pragma unroll
            for (int tn = 0; tn < 4; ++tn) {
                const bf16x8 vf = *(const bf16x8*)&Vs[tn * 16 + l15][g * 32 + quad * 8];
                o_acc[tn] = __builtin_amdgcn_mfma_f32_16x16x32_bf16(pf8[g], vf, o_acc[tn], 0, 0, 0);
            }
        }
    }

    l_sum += __shfl_xor(l_sum, 16, 64);
    l_sum += __shfl_xor(l_sum, 32, 64);

#pragma unroll
    for (int r = 0; r < 4; ++r) {
        const float Lv = __shfl(l_sum, quad * 4 + r, 64);
        const float inv = 1.0f / Lv;
        const int token = qt * 64 + wv * 16 + quad * 4 + r;
#pragma unroll
        for (int tn = 0; tn < 4; ++tn) {
            const int col = h * 64 + tn * 16 + l15;
            o[(size_t)(b * 1024 + token) * 768 + col] = f2b(o_acc[tn][r] * inv);
        }
    }
}

// ---------------------------------------------------------------------------
// Kernel 5: output projection, 128x128 tiles, K=768, +bias, fp32 out.
// ---------------------------------------------------------------------------
__global__ __launch_bounds__(256, 2) void gemm_proj(
    const u16* __restrict__ A, const u16* __restrict__ Bt,
    float* __restrict__ C, const float* __restrict__ bias)
{
    __shared__ u16 As[128 * 32];
    __shared__ u16 Bs[128 * 32];

    const int tid  = threadIdx.x;
    const int lane = tid & 63, wv = tid >> 6;
    const int l15  = lane & 15, quad = lane >> 4;
    const int rowBase = blockIdx.y * 128;
    const int colBase = blockIdx.x * 128;

    const int srow = wv * 32 + (lane >> 2);
    const int scol = (lane & 3) * 8;
    const u16* aSrc = A  + (size_t)(rowBase + srow) * 768 + scol;
    const u16* bSrc = Bt + (size_t)(colBase + srow) * 768 + scol;
    u16* aDst = As + wv * 1024;
    u16* bDst = Bs + wv * 1024;

    const f32x4 zero4 = {0.f, 0.f, 0.f, 0.f};
    f32x4 acc[4][4];
#pragma unroll
    for (int tm = 0; tm < 4; ++tm)
#pragma unroll
        for (int tn = 0; tn < 4; ++tn) acc[tm][tn] = zero4;

    const int wr = (wv >> 1) * 64, wc = (wv & 1) * 64;

    for (int kk = 0; kk < 768; kk += 32) {
        __syncthreads();
        g2l16(aSrc + kk,            aDst);
        g2l16(aSrc + kk + 16 * 768, aDst + 512);
        g2l16(bSrc + kk,            bDst);
        g2l16(bSrc + kk + 16 * 768, bDst + 512);
        __syncthreads();

        bf16x8 af[4], bfm[4];
#pragma unroll
        for (int t = 0; t < 4; ++t) {
            af[t]  = *(const bf16x8*)(As + (wr + t * 16 + l15) * 32 + quad * 8);
            bfm[t] = *(const bf16x8*)(Bs + (wc + t * 16 + l15) * 32 + quad * 8);
        }
#pragma unroll
        for (int tm = 0; tm < 4; ++tm)
#pragma unroll
            for (int tn = 0; tn < 4; ++tn)
                acc[tm][tn] = __builtin_amdgcn_mfma_f32_16x16x32_bf16(
                    af[tm], bfm[tn], acc[tm][tn], 0, 0, 0);
    }

#pragma unroll
    for (int tm = 0; tm < 4; ++tm) {
        const int grow = rowBase + wr + tm * 16 + quad * 4;
#pragma unroll
        for (int tn = 0; tn < 4; ++tn) {
            const int gcol = colBase + wc + tn * 16 + l15;
            const float bv = bias[gcol];
#pragma unroll
            for (int r = 0; r < 4; ++r)
                C[(size_t)(grow + r) * 768 + gcol] = acc[tm][tn][r] + bv;
        }
    }
}

// ---------------------------------------------------------------------------
extern "C" void kernel_launch(void* const* d_in, const int* in_sizes, int n_in,
                              void* d_out, int out_size, void* d_ws, size_t ws_size,
                              hipStream_t stream)
{
    const float* x      = (const float*)d_in[0];
    const float* Wq0    = (const float*)d_in[1];
    const float* Wq1    = (const float*)d_in[2];
    const float* Wq2    = (const float*)d_in[3];
    const float* Wk0    = (const float*)d_in[4];
    const float* Wk1    = (const float*)d_in[5];
    const float* Wk2    = (const float*)d_in[6];
    const float* Wv0    = (const float*)d_in[7];
    const float* Wv1    = (const float*)d_in[8];
    const float* Wv2    = (const float*)d_in[9];
    const float* proj_w = (const float*)d_in[10];
    const float* proj_b = (const float*)d_in[11];
    float* outp = (float*)d_out;

    char* ws = (char*)d_ws;
    u16* T    = (u16*)ws;                       // 8192*192*2 = 3,145,728 B
    u16* G    = (u16*)(ws + 3145728);           // 294,912 B
    u16* W0b  = (u16*)(ws + 3440640);           // 294,912 B
    u16* pwb  = (u16*)(ws + 3145728);           // 1,179,648 B — overwrites G/W0b after they're dead
    u16* xb   = (u16*)(ws + 4325376);           // 12,582,912 B
    u16* attn = xb;                             // aliases xb (dead after gemm_t)
    u16* qkv  = (u16*)(ws + 16908288);          // 37,748,736 B; end = 54,657,024 B

    cast_f32_bf16<<<6144, 256, 0, stream>>>(x, xb, 1572864);
    build_small<<<1152, 256, 0, stream>>>(Wq0, Wq1, Wq2, Wk0, Wk1, Wk2, Wv0, Wv1, Wv2, G, W0b);
    gemm_t<<<dim3(3, 128), 256, 0, stream>>>(xb, G, T);
    gemm_expand<<<dim3(18, 64), 256, 0, stream>>>(T, W0b, qkv);
    cast_f32_bf16<<<576, 256, 0, stream>>>(proj_w, pwb, 147456);   // after G/W0b are dead
    flash_attn4<<<dim3(16, 96), 256, 0, stream>>>(qkv, attn);
    gemm_proj<<<dim3(6, 64), 256, 0, stream>>>(attn, pwb, outp, proj_b);
}

// Round 6
// 185.906 us; speedup vs baseline: 1.3714x; 1.0378x over previous
//
#include <hip/hip_runtime.h>

typedef unsigned short u16;
typedef __attribute__((ext_vector_type(8))) short bf16x8;
typedef __attribute__((ext_vector_type(4))) float f32x4;
typedef __attribute__((ext_vector_type(4))) unsigned short u16x4;
typedef __attribute__((ext_vector_type(8))) unsigned short u16x8;

#define AS1 __attribute__((address_space(1)))
#define AS3 __attribute__((address_space(3)))

__device__ __forceinline__ float b2f(u16 s) {
    return __uint_as_float(((unsigned)s) << 16);
}
__device__ __forceinline__ u16 f2b(float f) {
    unsigned u = __float_as_uint(f);
    unsigned r = 0x7fffu + ((u >> 16) & 1u);
    return (u16)((u + r) >> 16);
}

// pack hi16(p1):hi16(p0) in one v_perm_b32 (truncating bf16 convert x2)
__device__ __forceinline__ unsigned packtrunc(float p0, float p1) {
#if __has_builtin(__builtin_amdgcn_perm)
    return __builtin_amdgcn_perm(__float_as_uint(p1), __float_as_uint(p0), 0x07060302u);
#else
    return (__float_as_uint(p0) >> 16) | (__float_as_uint(p1) & 0xffff0000u);
#endif
}

// async global->LDS, 16B per lane
__device__ __forceinline__ void g2l16(const u16* g, u16* l) {
    __builtin_amdgcn_global_load_lds((const AS1 void*)g, (AS3 void*)l, 16, 0, 0);
}

#if __has_builtin(__builtin_amdgcn_exp2f)
#define EXP2(x) __builtin_amdgcn_exp2f(x)
#else
#define EXP2(x) exp2f(x)
#endif

// ---------------------------------------------------------------------------
// Kernel 1: weight prep.
//   G[row = which*64 + r][c = h*64+d] = W1w[h,r] * W2w[d,r]        (192 x 768)
//   W0b[row = which*768 + mm][r]      = W0w[mm,r] * scale_which    (2304 x 64)
//   pwb = bf16(proj_w)                                             (768 x 768)
// scale_Q = 0.125 * log2(e)  (flash uses exp2)
// ---------------------------------------------------------------------------
__global__ __launch_bounds__(256) void build_small(
    const float* __restrict__ Wq0, const float* __restrict__ Wq1, const float* __restrict__ Wq2,
    const float* __restrict__ Wk0, const float* __restrict__ Wk1, const float* __restrict__ Wk2,
    const float* __restrict__ Wv0, const float* __restrict__ Wv1, const float* __restrict__ Wv2,
    const float* __restrict__ PW,
    u16* __restrict__ G, u16* __restrict__ W0b, u16* __restrict__ pwb)
{
    const int idx = blockIdx.x * 256 + threadIdx.x;
    if (idx < 147456) {
        const int row = idx / 768, c = idx - row * 768;
        const int which = row >> 6, r = row & 63;
        const int h = c >> 6, d = c & 63;
        const float* W1 = (which == 0) ? Wq1 : (which == 1) ? Wk1 : Wv1;
        const float* W2 = (which == 0) ? Wq2 : (which == 1) ? Wk2 : Wv2;
        G[idx] = f2b(W1[h * 64 + r] * W2[d * 64 + r]);
    } else if (idx < 294912) {
        const int j = idx - 147456;
        const int row = j >> 6, r = j & 63;
        const int which = row / 768, mm = row - which * 768;
        const float* W0 = (which == 0) ? Wq0 : (which == 1) ? Wk0 : Wv0;
        const float scale = (which == 0) ? 0.125f * 1.4426950408889634f : 1.0f;
        W0b[j] = f2b(W0[mm * 64 + r] * scale);
    } else {
        const int j = idx - 294912;             // 0..147455 float4 chunks
        const float4 v = ((const float4*)PW)[j];
        u16x4 o;
        o.x = f2b(v.x); o.y = f2b(v.y); o.z = f2b(v.z); o.w = f2b(v.w);
        ((u16x4*)pwb)[j] = o;
    }
}

// ---------------------------------------------------------------------------
// Kernel 2: t = x(fp32) @ G^T-layout (M=8192, N=192, K=768). 64x64 tiles,
// grid (3,128). x converted to bf16 in-register during staging (no cast pass).
// Register-prefetch: barrier drains only lgkm, global latency overlapped.
// ---------------------------------------------------------------------------
__global__ __launch_bounds__(256, 2) void gemm_t(
    const float* __restrict__ X, const u16* __restrict__ G, u16* __restrict__ T)
{
    __shared__ u16 As[64 * 32];
    __shared__ u16 Bs[64 * 32];

    const int tid = threadIdx.x;
    const int lane = tid & 63, wv = tid >> 6;
    const int l15 = lane & 15, quad = lane >> 4;
    const int rowBase = blockIdx.y * 64;
    const int colBase = blockIdx.x * 64;

    const int srow = tid >> 2;          // 0..63
    const int scol = (tid & 3) * 8;     // 0/8/16/24
    const float* aS = X + (size_t)(rowBase + srow) * 768 + scol;
    const u16*  bS  = G + (size_t)(colBase + srow) * 768 + scol;

    float4 a0 = *(const float4*)(aS);
    float4 a1 = *(const float4*)(aS + 4);
    int4   b0 = *(const int4*)(bS);

    const f32x4 zero4 = {0.f, 0.f, 0.f, 0.f};
    f32x4 acc[4];
#pragma unroll
    for (int tn = 0; tn < 4; ++tn) acc[tn] = zero4;

    for (int kk = 0; kk < 768; kk += 32) {
        __syncthreads();
        u16x8 ap;
        ap[0] = f2b(a0.x); ap[1] = f2b(a0.y); ap[2] = f2b(a0.z); ap[3] = f2b(a0.w);
        ap[4] = f2b(a1.x); ap[5] = f2b(a1.y); ap[6] = f2b(a1.z); ap[7] = f2b(a1.w);
        *(u16x8*)&As[srow * 32 + scol] = ap;
        *(int4*)&Bs[srow * 32 + scol]  = b0;
        __syncthreads();

        if (kk < 736) {
            a0 = *(const float4*)(aS + kk + 32);
            a1 = *(const float4*)(aS + kk + 36);
            b0 = *(const int4*)(bS + kk + 32);
        }

        const bf16x8 af = *(const bf16x8*)(As + (wv * 16 + l15) * 32 + quad * 8);
#pragma unroll
        for (int tn = 0; tn < 4; ++tn) {
            const bf16x8 bf = *(const bf16x8*)(Bs + (tn * 16 + l15) * 32 + quad * 8);
            acc[tn] = __builtin_amdgcn_mfma_f32_16x16x32_bf16(af, bf, acc[tn], 0, 0, 0);
        }
    }

#pragma unroll
    for (int tn = 0; tn < 4; ++tn) {
        const int col = colBase + tn * 16 + l15;
#pragma unroll
        for (int r = 0; r < 4; ++r) {
            const int grow = rowBase + wv * 16 + quad * 4 + r;
            T[(size_t)grow * 192 + col] = f2b(acc[tn][r]);
        }
    }
}

// ---------------------------------------------------------------------------
// Kernel 3: qkv = t @ W0b^T  (K=64). 128x128 tiles, grid (18,64).
// Epilogue scatters q,k as [bh][l][d]; V stored TRANSPOSED vt[bh][d][l].
// ---------------------------------------------------------------------------
__global__ __launch_bounds__(256, 2) void gemm_expand(
    const u16* __restrict__ T, const u16* __restrict__ W0b, u16* __restrict__ qkvp)
{
    __shared__ u16 As[128 * 32];
    __shared__ u16 Bs[128 * 32];

    const int tid  = threadIdx.x;
    const int lane = tid & 63, wv = tid >> 6;
    const int l15  = lane & 15, quad = lane >> 4;
    const int rowBase = blockIdx.y * 128;
    const int colBase = blockIdx.x * 128;
    const int which = blockIdx.x / 6;           // 0=Q,1=K,2=V

    const int srow = wv * 32 + (lane >> 2);
    const int scol = (lane & 3) * 8;
    const u16* aSrc = T   + (size_t)(rowBase + srow) * 192 + which * 64 + scol;
    const u16* bSrc = W0b + (size_t)(colBase + srow) * 64 + scol;
    u16* aDst = As + wv * 1024;
    u16* bDst = Bs + wv * 1024;

    const f32x4 zero4 = {0.f, 0.f, 0.f, 0.f};
    f32x4 acc[4][4];
#pragma unroll
    for (int tm = 0; tm < 4; ++tm)
#pragma unroll
        for (int tn = 0; tn < 4; ++tn) acc[tm][tn] = zero4;

    const int wr = (wv >> 1) * 64, wc = (wv & 1) * 64;

    for (int kk = 0; kk < 64; kk += 32) {
        __syncthreads();
        g2l16(aSrc + kk,            aDst);
        g2l16(aSrc + kk + 16 * 192, aDst + 512);
        g2l16(bSrc + kk,            bDst);
        g2l16(bSrc + kk + 16 * 64,  bDst + 512);
        __syncthreads();

        bf16x8 af[4], bfm[4];
#pragma unroll
        for (int t = 0; t < 4; ++t) {
            af[t]  = *(const bf16x8*)(As + (wr + t * 16 + l15) * 32 + quad * 8);
            bfm[t] = *(const bf16x8*)(Bs + (wc + t * 16 + l15) * 32 + quad * 8);
        }
#pragma unroll
        for (int tm = 0; tm < 4; ++tm)
#pragma unroll
            for (int tn = 0; tn < 4; ++tn)
                acc[tm][tn] = __builtin_amdgcn_mfma_f32_16x16x32_bf16(
                    af[tm], bfm[tn], acc[tm][tn], 0, 0, 0);
    }

    const int mmBase = colBase - which * 768 + wc;
    if (which < 2) {
        u16* outp = qkvp + (size_t)which * 6291456;
#pragma unroll
        for (int tm = 0; tm < 4; ++tm) {
            const int grow = rowBase + wr + tm * 16 + quad * 4;
            const int b = grow >> 10, l = grow & 1023;
#pragma unroll
            for (int tn = 0; tn < 4; ++tn) {
                const int mmv = mmBase + tn * 16 + l15;
                const int h = mmv >> 6, d = mmv & 63;
                const size_t base = (((size_t)(b * 12 + h) * 1024 + l) << 6) + d;
#pragma unroll
                for (int r = 0; r < 4; ++r)
                    outp[base + (size_t)r * 64] = f2b(acc[tm][tn][r]);
            }
        }
    } else {
        u16* outp = qkvp + (size_t)2 * 6291456;
#pragma unroll
        for (int tm = 0; tm < 4; ++tm) {
            const int grow = rowBase + wr + tm * 16 + quad * 4;
            const int b = grow >> 10, l = grow & 1023;
#pragma unroll
            for (int tn = 0; tn < 4; ++tn) {
                const int mmv = mmBase + tn * 16 + l15;
                const int h = mmv >> 6, d = mmv & 63;
                u16x4 pk;
                pk.x = f2b(acc[tm][tn][0]); pk.y = f2b(acc[tm][tn][1]);
                pk.z = f2b(acc[tm][tn][2]); pk.w = f2b(acc[tm][tn][3]);
                *(u16x4*)(outp + (((size_t)(b * 12 + h) * 64 + d) << 10) + l) = pk;
            }
        }
    }
}

// ---------------------------------------------------------------------------
// Kernel 4: flash attention v5. Grid (8,96): block = 128 q rows, 4 waves,
// 32 q rows/wave (2 q-groups of 16). Same LDS traffic as v4 feeds 2x the MFMAs.
// - K staged bit-permuted so S^T exits in K=32 PV A-operand layout.
// - P packed by truncation (v_perm); exact normalization via ones-column MFMA
//   (L = sum of the SAME bf16 P used in PV, so rounding bias cancels in O/L).
// ---------------------------------------------------------------------------
__global__ __launch_bounds__(256, 3) void flash_attn5(
    const u16* __restrict__ qkv, u16* __restrict__ o)
{
    const int qt = blockIdx.x;          // 0..7 (128 q rows each)
    const int bh = blockIdx.y;          // 0..95
    const int b = bh / 12, h = bh - b * 12;
    const u16* qp = qkv + (size_t)bh * 65536 + qt * 8192;
    const u16* kp = qkv + 6291456 + (size_t)bh * 65536;
    const u16* vp = qkv + 2 * 6291456 + (size_t)bh * 65536;   // vt [d][l]

    __shared__ u16 Ks[64][72];
    __shared__ u16 Vs[64][72];          // Vs[d][key]

    const int t = threadIdx.x;
    const int lane = t & 63, wv = t >> 6;
    const int l15 = lane & 15, quad = lane >> 4;

    // Q fragments: 2 q-groups x 2 k-halves
    bf16x8 qf[2][2];
#pragma unroll
    for (int qg = 0; qg < 2; ++qg) {
        qf[qg][0] = *(const bf16x8*)(qp + (wv * 32 + qg * 16 + l15) * 64 + quad * 8);
        qf[qg][1] = *(const bf16x8*)(qp + (wv * 32 + qg * 16 + l15) * 64 + 32 + quad * 8);
    }

    const int srow = t >> 2;            // physical key / d row 0..63
    const int scol = (t & 3) * 16;
    const int p5 = srow & 31;
    const int lrow = (srow & 32) | ((p5 & 4) << 2) | ((p5 & 16) >> 1)
                   | ((p5 & 8) >> 1) | (p5 & 3);   // permuted K row

    // ones B-fragment: B[n=0][k]=1 -> lanes with l15==0 hold 1.0 for all k
    bf16x8 vone = {};
    if (l15 == 0) {
#pragma unroll
        for (int j = 0; j < 8; ++j) vone[j] = (short)0x3F80;
    }

    // prefetch tile 0
    int4 kr0 = *(const int4*)(kp + srow * 64 + scol);
    int4 kr1 = *(const int4*)(kp + srow * 64 + scol + 8);
    int4 vr0 = *(const int4*)(vp + srow * 1024 + scol);
    int4 vr1 = *(const int4*)(vp + srow * 1024 + scol + 8);

    const f32x4 zero4 = {0.f, 0.f, 0.f, 0.f};
    f32x4 o_acc[2][4];
    f32x4 Lacc[2] = {zero4, zero4};
#pragma unroll
    for (int qg = 0; qg < 2; ++qg)
#pragma unroll
        for (int tn = 0; tn < 4; ++tn) o_acc[qg][tn] = zero4;

    for (int kt = 0; kt < 16; ++kt) {
        __syncthreads();
        *(int4*)&Ks[lrow][scol]     = kr0;
        *(int4*)&Ks[lrow][scol + 8] = kr1;
        *(int4*)&Vs[srow][scol]     = vr0;
        *(int4*)&Vs[srow][scol + 8] = vr1;
        __syncthreads();

        if (kt < 15) {
            kr0 = *(const int4*)(kp + (kt + 1) * 4096 + srow * 64 + scol);
            kr1 = *(const int4*)(kp + (kt + 1) * 4096 + srow * 64 + scol + 8);
            vr0 = *(const int4*)(vp + srow * 1024 + (kt + 1) * 64 + scol);
            vr1 = *(const int4*)(vp + srow * 1024 + (kt + 1) * 64 + scol + 8);
        }

        // S^T = K x Q^T (keys permuted per tile); K-fragments shared by both q-groups
        f32x4 Sacc[2][4];
#pragma unroll
        for (int qg = 0; qg < 2; ++qg)
#pragma unroll
            for (int tk = 0; tk < 4; ++tk) Sacc[qg][tk] = zero4;
#pragma unroll
        for (int ks = 0; ks < 2; ++ks) {
#pragma unroll
            for (int tk = 0; tk < 4; ++tk) {
                const bf16x8 kf = *(const bf16x8*)&Ks[tk * 16 + l15][ks * 32 + quad * 8];
                Sacc[0][tk] = __builtin_amdgcn_mfma_f32_16x16x32_bf16(kf, qf[0][ks], Sacc[0][tk], 0, 0, 0);
                Sacc[1][tk] = __builtin_amdgcn_mfma_f32_16x16x32_bf16(kf, qf[1][ks], Sacc[1][tk], 0, 0, 0);
            }
        }

        // P = exp2(S'), truncation-packed into K=32 A-fragments
        union { bf16x8 v; unsigned u[4]; } pf[2][2];
#pragma unroll
        for (int qg = 0; qg < 2; ++qg)
#pragma unroll
            for (int tk = 0; tk < 4; ++tk) {
                const float p0 = EXP2(Sacc[qg][tk][0]);
                const float p1 = EXP2(Sacc[qg][tk][1]);
                const float p2 = EXP2(Sacc[qg][tk][2]);
                const float p3 = EXP2(Sacc[qg][tk][3]);
                const int g = tk >> 1, hf = (tk & 1) * 2;
                pf[qg][g].u[hf + 0] = packtrunc(p0, p1);
                pf[qg][g].u[hf + 1] = packtrunc(p2, p3);
            }

        // O += P V (full-rate K=32), L += P * ones (exact normalizer, no VALU)
#pragma unroll
        for (int g = 0; g < 2; ++g) {
#pragma unroll
            for (int tn = 0; tn < 4; ++tn) {
                const bf16x8 vf = *(const bf16x8*)&Vs[tn * 16 + l15][g * 32 + quad * 8];
                o_acc[0][tn] = __builtin_amdgcn_mfma_f32_16x16x32_bf16(pf[0][g].v, vf, o_acc[0][tn], 0, 0, 0);
                o_acc[1][tn] = __builtin_amdgcn_mfma_f32_16x16x32_bf16(pf[1][g].v, vf, o_acc[1][tn], 0, 0, 0);
            }
            Lacc[0] = __builtin_amdgcn_mfma_f32_16x16x32_bf16(pf[0][g].v, vone, Lacc[0], 0, 0, 0);
            Lacc[1] = __builtin_amdgcn_mfma_f32_16x16x32_bf16(pf[1][g].v, vone, Lacc[1], 0, 0, 0);
        }
    }

    // epilogue: O[q_local = quad*4+r][d = tn*16+l15]; L[q=quad*4+r] lives at
    // lane quad*16 (l15==0), register r of Lacc.
#pragma unroll
    for (int qg = 0; qg < 2; ++qg) {
#pragma unroll
        for (int r = 0; r < 4; ++r) {
            const float Lv = __shfl(Lacc[qg][r], quad << 4, 64);
            const float inv = 1.0f / Lv;
            const int token = qt * 128 + wv * 32 + qg * 16 + quad * 4 + r;
#pragma unroll
            for (int tn = 0; tn < 4; ++tn) {
                const int col = h * 64 + tn * 16 + l15;
                o[(size_t)(b * 1024 + token) * 768 + col] = f2b(o_acc[qg][tn][r] * inv);
            }
        }
    }
}

// ---------------------------------------------------------------------------
// Kernel 5: output projection, 128x128 tiles, K=768, +bias, fp32 out.
// ---------------------------------------------------------------------------
__global__ __launch_bounds__(256, 2) void gemm_proj(
    const u16* __restrict__ A, const u16* __restrict__ Bt,
    float* __restrict__ C, const float* __restrict__ bias)
{
    __shared__ u16 As[128 * 32];
    __shared__ u16 Bs[128 * 32];

    const int tid  = threadIdx.x;
    const int lane = tid & 63, wv = tid >> 6;
    const int l15  = lane & 15, quad = lane >> 4;
    const int rowBase = blockIdx.y * 128;
    const int colBase = blockIdx.x * 128;

    const int srow = wv * 32 + (lane >> 2);
    const int scol = (lane & 3) * 8;
    const u16* aSrc = A  + (size_t)(rowBase + srow) * 768 + scol;
    const u16* bSrc = Bt + (size_t)(colBase + srow) * 768 + scol;
    u16* aDst = As + wv * 1024;
    u16* bDst = Bs + wv * 1024;

    const f32x4 zero4 = {0.f, 0.f, 0.f, 0.f};
    f32x4 acc[4][4];
#pragma unroll
    for (int tm = 0; tm < 4; ++tm)
#pragma unroll
        for (int tn = 0; tn < 4; ++tn) acc[tm][tn] = zero4;

    const int wr = (wv >> 1) * 64, wc = (wv & 1) * 64;

    for (int kk = 0; kk < 768; kk += 32) {
        __syncthreads();
        g2l16(aSrc + kk,            aDst);
        g2l16(aSrc + kk + 16 * 768, aDst + 512);
        g2l16(bSrc + kk,            bDst);
        g2l16(bSrc + kk + 16 * 768, bDst + 512);
        __syncthreads();

        bf16x8 af[4], bfm[4];
#pragma unroll
        for (int t = 0; t < 4; ++t) {
            af[t]  = *(const bf16x8*)(As + (wr + t * 16 + l15) * 32 + quad * 8);
            bfm[t] = *(const bf16x8*)(Bs + (wc + t * 16 + l15) * 32 + quad * 8);
        }
#pragma unroll
        for (int tm = 0; tm < 4; ++tm)
#pragma unroll
            for (int tn = 0; tn < 4; ++tn)
                acc[tm][tn] = __builtin_amdgcn_mfma_f32_16x16x32_bf16(
                    af[tm], bfm[tn], acc[tm][tn], 0, 0, 0);
    }

#pragma unroll
    for (int tm = 0; tm < 4; ++tm) {
        const int grow = rowBase + wr + tm * 16 + quad * 4;
#pragma unroll
        for (int tn = 0; tn < 4; ++tn) {
            const int gcol = colBase + wc + tn * 16 + l15;
            const float bv = bias[gcol];
#pragma unroll
            for (int r = 0; r < 4; ++r)
                C[(size_t)(grow + r) * 768 + gcol] = acc[tm][tn][r] + bv;
        }
    }
}

// ---------------------------------------------------------------------------
extern "C" void kernel_launch(void* const* d_in, const int* in_sizes, int n_in,
                              void* d_out, int out_size, void* d_ws, size_t ws_size,
                              hipStream_t stream)
{
    const float* x      = (const float*)d_in[0];
    const float* Wq0    = (const float*)d_in[1];
    const float* Wq1    = (const float*)d_in[2];
    const float* Wq2    = (const float*)d_in[3];
    const float* Wk0    = (const float*)d_in[4];
    const float* Wk1    = (const float*)d_in[5];
    const float* Wk2    = (const float*)d_in[6];
    const float* Wv0    = (const float*)d_in[7];
    const float* Wv1    = (const float*)d_in[8];
    const float* Wv2    = (const float*)d_in[9];
    const float* proj_w = (const float*)d_in[10];
    const float* proj_b = (const float*)d_in[11];
    float* outp = (float*)d_out;

    char* ws = (char*)d_ws;
    u16* T    = (u16*)ws;                       // 3,145,728 B
    u16* G    = (u16*)(ws + 3145728);           // 294,912 B
    u16* W0b  = (u16*)(ws + 3440640);           // 294,912 B
    u16* pwb  = (u16*)(ws + 3735552);           // 1,179,648 B
    u16* attn = (u16*)(ws + 4915200);           // 12,582,912 B
    u16* qkv  = (u16*)(ws + 17498112);          // 37,748,736 B; end = 55,246,848 B

    build_small<<<1728, 256, 0, stream>>>(Wq0, Wq1, Wq2, Wk0, Wk1, Wk2, Wv0, Wv1, Wv2,
                                          proj_w, G, W0b, pwb);
    gemm_t<<<dim3(3, 128), 256, 0, stream>>>(x, G, T);
    gemm_expand<<<dim3(18, 64), 256, 0, stream>>>(T, W0b, qkv);
    flash_attn5<<<dim3(8, 96), 256, 0, stream>>>(qkv, attn);
    gemm_proj<<<dim3(6, 64), 256, 0, stream>>>(attn, pwb, outp, proj_b);
}

// Round 7
// 180.101 us; speedup vs baseline: 1.4156x; 1.0322x over previous
//
#include <hip/hip_runtime.h>

typedef unsigned short u16;
typedef __attribute__((ext_vector_type(8))) short bf16x8;
typedef __attribute__((ext_vector_type(4))) float f32x4;
typedef __attribute__((ext_vector_type(4))) unsigned short u16x4;
typedef __attribute__((ext_vector_type(8))) unsigned short u16x8;

#define AS1 __attribute__((address_space(1)))
#define AS3 __attribute__((address_space(3)))

__device__ __forceinline__ float b2f(u16 s) {
    return __uint_as_float(((unsigned)s) << 16);
}
__device__ __forceinline__ u16 f2b(float f) {
    unsigned u = __float_as_uint(f);
    unsigned r = 0x7fffu + ((u >> 16) & 1u);
    return (u16)((u + r) >> 16);
}

// pack hi16(p1):hi16(p0) in one v_perm_b32 (truncating bf16 convert x2)
__device__ __forceinline__ unsigned packtrunc(float p0, float p1) {
#if __has_builtin(__builtin_amdgcn_perm)
    return __builtin_amdgcn_perm(__float_as_uint(p1), __float_as_uint(p0), 0x07060302u);
#else
    return (__float_as_uint(p0) >> 16) | (__float_as_uint(p1) & 0xffff0000u);
#endif
}

// async global->LDS, 16B per lane
__device__ __forceinline__ void g2l16(const u16* g, u16* l) {
    __builtin_amdgcn_global_load_lds((const AS1 void*)g, (AS3 void*)l, 16, 0, 0);
}

#if __has_builtin(__builtin_amdgcn_exp2f)
#define EXP2(x) __builtin_amdgcn_exp2f(x)
#else
#define EXP2(x) exp2f(x)
#endif

// ---------------------------------------------------------------------------
// Kernel 1: weight prep (two sections by blockIdx).
// A (bx < 1152): elementwise
//   G[which*64+r][c=h*64+d] = W1[h,r]*W2[d,r]          (192 x 768)
//   W0b[which*768+mm][r]    = W0[mm,r]*scale_which     (2304 x 64; V rows unused)
// B (bx >= 1152): Dcat[m][h*64+r] = sum_d PW[m,h*64+d] * Wv0[h*64+d,r]
//   (proj_w folded with W0v; 288 blocks of 32 m-rows x one head)
// scale_Q = 0.125 * log2(e)  (flash uses exp2)
// ---------------------------------------------------------------------------
__global__ __launch_bounds__(256) void build_prep(
    const float* __restrict__ Wq0, const float* __restrict__ Wq1, const float* __restrict__ Wq2,
    const float* __restrict__ Wk0, const float* __restrict__ Wk1, const float* __restrict__ Wk2,
    const float* __restrict__ Wv0, const float* __restrict__ Wv1, const float* __restrict__ Wv2,
    const float* __restrict__ PW,
    u16* __restrict__ G, u16* __restrict__ W0b, u16* __restrict__ Dcat)
{
    const int bx = blockIdx.x;
    const int t = threadIdx.x;
    if (bx < 1152) {
        const int idx = bx * 256 + t;
        if (idx < 147456) {
            const int row = idx / 768, c = idx - row * 768;
            const int which = row >> 6, r = row & 63;
            const int h = c >> 6, d = c & 63;
            const float* W1 = (which == 0) ? Wq1 : (which == 1) ? Wk1 : Wv1;
            const float* W2 = (which == 0) ? Wq2 : (which == 1) ? Wk2 : Wv2;
            G[idx] = f2b(W1[h * 64 + r] * W2[d * 64 + r]);
        } else {
            const int j = idx - 147456;
            const int row = j >> 6, r = j & 63;
            const int which = row / 768, mm = row - which * 768;
            const float* W0 = (which == 0) ? Wq0 : (which == 1) ? Wk0 : Wv0;
            const float scale = (which == 0) ? 0.125f * 1.4426950408889634f : 1.0f;
            W0b[j] = f2b(W0[mm * 64 + r] * scale);
        }
    } else {
        __shared__ float w0s[64 * 65];   // w0s[d][r] = Wv0[h*64+d][r]
        __shared__ float pws[32 * 65];   // pws[mi][d] = PW[mBase+mi][h*64+d]
        const int hb = bx - 1152;        // 0..287
        const int h = hb / 24, mBase = (hb - h * 24) * 32;
        for (int i = t; i < 4096; i += 256) {
            const int d = i >> 6, r = i & 63;
            w0s[d * 65 + r] = Wv0[(h * 64 + d) * 64 + r];
        }
        for (int i = t; i < 2048; i += 256) {
            const int mi = i >> 6, d = i & 63;
            pws[mi * 65 + d] = PW[(size_t)(mBase + mi) * 768 + h * 64 + d];
        }
        __syncthreads();
        const int r = t & 63, mi0 = t >> 6;
        float w0c[64];
#pragma unroll
        for (int d = 0; d < 64; ++d) w0c[d] = w0s[d * 65 + r];
        for (int mi = mi0; mi < 32; mi += 4) {
            float acc = 0.f;
#pragma unroll
            for (int d = 0; d < 64; ++d) acc += pws[mi * 65 + d] * w0c[d];
            Dcat[(size_t)(mBase + mi) * 768 + h * 64 + r] = f2b(acc);
        }
    }
}

// ---------------------------------------------------------------------------
// Kernel 2: t = x(fp32) @ G^T-layout (M=8192, K=768). Grid (3,128), 64x64 tile.
// Col-tiles 0,1 (q,k parts) -> T[8192][128]; col-tile 2 (v part) -> tvt[64][8192]
// (transposed, packed 8B stores). x converted bf16 in-register during staging.
// ---------------------------------------------------------------------------
__global__ __launch_bounds__(256, 2) void gemm_t(
    const float* __restrict__ X, const u16* __restrict__ G,
    u16* __restrict__ T, u16* __restrict__ tvt)
{
    __shared__ u16 As[64 * 32];
    __shared__ u16 Bs[64 * 32];

    const int tid = threadIdx.x;
    const int lane = tid & 63, wv = tid >> 6;
    const int l15 = lane & 15, quad = lane >> 4;
    const int rowBase = blockIdx.y * 64;
    const int colBase = blockIdx.x * 64;

    const int srow = tid >> 2;          // 0..63
    const int scol = (tid & 3) * 8;     // 0/8/16/24
    const float* aS = X + (size_t)(rowBase + srow) * 768 + scol;
    const u16*  bS  = G + (size_t)(colBase + srow) * 768 + scol;

    float4 a0 = *(const float4*)(aS);
    float4 a1 = *(const float4*)(aS + 4);
    int4   b0 = *(const int4*)(bS);

    const f32x4 zero4 = {0.f, 0.f, 0.f, 0.f};
    f32x4 acc[4];
#pragma unroll
    for (int tn = 0; tn < 4; ++tn) acc[tn] = zero4;

    for (int kk = 0; kk < 768; kk += 32) {
        __syncthreads();
        u16x8 ap;
        ap[0] = f2b(a0.x); ap[1] = f2b(a0.y); ap[2] = f2b(a0.z); ap[3] = f2b(a0.w);
        ap[4] = f2b(a1.x); ap[5] = f2b(a1.y); ap[6] = f2b(a1.z); ap[7] = f2b(a1.w);
        *(u16x8*)&As[srow * 32 + scol] = ap;
        *(int4*)&Bs[srow * 32 + scol]  = b0;
        __syncthreads();

        if (kk < 736) {
            a0 = *(const float4*)(aS + kk + 32);
            a1 = *(const float4*)(aS + kk + 36);
            b0 = *(const int4*)(bS + kk + 32);
        }

        const bf16x8 af = *(const bf16x8*)(As + (wv * 16 + l15) * 32 + quad * 8);
#pragma unroll
        for (int tn = 0; tn < 4; ++tn) {
            const bf16x8 bf = *(const bf16x8*)(Bs + (tn * 16 + l15) * 32 + quad * 8);
            acc[tn] = __builtin_amdgcn_mfma_f32_16x16x32_bf16(af, bf, acc[tn], 0, 0, 0);
        }
    }

    if (colBase < 128) {
#pragma unroll
        for (int tn = 0; tn < 4; ++tn) {
            const int col = colBase + tn * 16 + l15;
#pragma unroll
            for (int r = 0; r < 4; ++r) {
                const int grow = rowBase + wv * 16 + quad * 4 + r;
                T[(size_t)grow * 128 + col] = f2b(acc[tn][r]);
            }
        }
    } else {
        // v-part: write transposed tvt[r'][token], 4 tokens packed per store
#pragma unroll
        for (int tn = 0; tn < 4; ++tn) {
            const int rr = tn * 16 + l15;                    // r index 0..63
            const int grow = rowBase + wv * 16 + quad * 4;   // token base
            u16x4 pk;
            pk.x = f2b(acc[tn][0]); pk.y = f2b(acc[tn][1]);
            pk.z = f2b(acc[tn][2]); pk.w = f2b(acc[tn][3]);
            *(u16x4*)(tvt + (size_t)rr * 8192 + grow) = pk;
        }
    }
}

// ---------------------------------------------------------------------------
// Kernel 3: q,k = t_qk @ W0b^T  (K=64). 128x128 tiles, grid (12,64).
// Scatters q,k as [bh][l][d].
// ---------------------------------------------------------------------------
__global__ __launch_bounds__(256, 2) void gemm_expand(
    const u16* __restrict__ T, const u16* __restrict__ W0b, u16* __restrict__ qkp)
{
    __shared__ u16 As[128 * 32];
    __shared__ u16 Bs[128 * 32];

    const int tid  = threadIdx.x;
    const int lane = tid & 63, wv = tid >> 6;
    const int l15  = lane & 15, quad = lane >> 4;
    const int rowBase = blockIdx.y * 128;
    const int colBase = blockIdx.x * 128;
    const int which = blockIdx.x / 6;           // 0=Q,1=K

    const int srow = wv * 32 + (lane >> 2);
    const int scol = (lane & 3) * 8;
    const u16* aSrc = T   + (size_t)(rowBase + srow) * 128 + which * 64 + scol;
    const u16* bSrc = W0b + (size_t)(colBase + srow) * 64 + scol;
    u16* aDst = As + wv * 1024;
    u16* bDst = Bs + wv * 1024;

    const f32x4 zero4 = {0.f, 0.f, 0.f, 0.f};
    f32x4 acc[4][4];
#pragma unroll
    for (int tm = 0; tm < 4; ++tm)
#pragma unroll
        for (int tn = 0; tn < 4; ++tn) acc[tm][tn] = zero4;

    const int wr = (wv >> 1) * 64, wc = (wv & 1) * 64;

    for (int kk = 0; kk < 64; kk += 32) {
        __syncthreads();
        g2l16(aSrc + kk,            aDst);
        g2l16(aSrc + kk + 16 * 128, aDst + 512);
        g2l16(bSrc + kk,            bDst);
        g2l16(bSrc + kk + 16 * 64,  bDst + 512);
        __syncthreads();

        bf16x8 af[4], bfm[4];
#pragma unroll
        for (int t = 0; t < 4; ++t) {
            af[t]  = *(const bf16x8*)(As + (wr + t * 16 + l15) * 32 + quad * 8);
            bfm[t] = *(const bf16x8*)(Bs + (wc + t * 16 + l15) * 32 + quad * 8);
        }
#pragma unroll
        for (int tm = 0; tm < 4; ++tm)
#pragma unroll
            for (int tn = 0; tn < 4; ++tn)
                acc[tm][tn] = __builtin_amdgcn_mfma_f32_16x16x32_bf16(
                    af[tm], bfm[tn], acc[tm][tn], 0, 0, 0);
    }

    const int mmBase = colBase - which * 768 + wc;
    u16* outp = qkp + (size_t)which * 6291456;
#pragma unroll
    for (int tm = 0; tm < 4; ++tm) {
        const int grow = rowBase + wr + tm * 16 + quad * 4;
        const int b = grow >> 10, l = grow & 1023;
#pragma unroll
        for (int tn = 0; tn < 4; ++tn) {
            const int mmv = mmBase + tn * 16 + l15;
            const int h = mmv >> 6, d = mmv & 63;
            const size_t base = (((size_t)(b * 12 + h) * 1024 + l) << 6) + d;
#pragma unroll
            for (int r = 0; r < 4; ++r)
                outp[base + (size_t)r * 64] = f2b(acc[tm][tn][r]);
        }
    }
}

// ---------------------------------------------------------------------------
// Kernel 4: flash attention v6 in t-space. Grid (8,96): block = 128 q rows,
// 4 waves x 32 q rows. Z_h = P_h @ t_v written to Zcat[l][h*64+r] (proj folded
// into Dcat). K staged bit-permuted (S^T exits in K=32 PV A-layout); P packed
// by truncation; normalizer L via ones-column MFMA.
// ---------------------------------------------------------------------------
__global__ __launch_bounds__(256, 3) void flash_attn6(
    const u16* __restrict__ qk, const u16* __restrict__ tvt, u16* __restrict__ Z)
{
    const int qt = blockIdx.x;          // 0..7 (128 q rows each)
    const int bh = blockIdx.y;          // 0..95
    const int b = bh / 12, h = bh - b * 12;
    const u16* qp = qk + (size_t)bh * 65536 + qt * 8192;
    const u16* kp = qk + 6291456 + (size_t)bh * 65536;
    const u16* vp = tvt + b * 1024;     // tvt[r][8192], our slice cols b*1024..

    __shared__ u16 Ks[64][72];
    __shared__ u16 Vs[64][72];          // Vs[r][key]

    const int t = threadIdx.x;
    const int lane = t & 63, wv = t >> 6;
    const int l15 = lane & 15, quad = lane >> 4;

    bf16x8 qf[2][2];
#pragma unroll
    for (int qg = 0; qg < 2; ++qg) {
        qf[qg][0] = *(const bf16x8*)(qp + (wv * 32 + qg * 16 + l15) * 64 + quad * 8);
        qf[qg][1] = *(const bf16x8*)(qp + (wv * 32 + qg * 16 + l15) * 64 + 32 + quad * 8);
    }

    const int srow = t >> 2;            // key-row / r-row 0..63
    const int scol = (t & 3) * 16;
    const int p5 = srow & 31;
    const int lrow = (srow & 32) | ((p5 & 4) << 2) | ((p5 & 16) >> 1)
                   | ((p5 & 8) >> 1) | (p5 & 3);   // permuted K row

    bf16x8 vone = {};
    if (l15 == 0) {
#pragma unroll
        for (int j = 0; j < 8; ++j) vone[j] = (short)0x3F80;
    }

    int4 kr0 = *(const int4*)(kp + srow * 64 + scol);
    int4 kr1 = *(const int4*)(kp + srow * 64 + scol + 8);
    int4 vr0 = *(const int4*)(vp + (size_t)srow * 8192 + scol);
    int4 vr1 = *(const int4*)(vp + (size_t)srow * 8192 + scol + 8);

    const f32x4 zero4 = {0.f, 0.f, 0.f, 0.f};
    f32x4 o_acc[2][4];
    f32x4 Lacc[2] = {zero4, zero4};
#pragma unroll
    for (int qg = 0; qg < 2; ++qg)
#pragma unroll
        for (int tn = 0; tn < 4; ++tn) o_acc[qg][tn] = zero4;

    for (int kt = 0; kt < 16; ++kt) {
        __syncthreads();
        *(int4*)&Ks[lrow][scol]     = kr0;
        *(int4*)&Ks[lrow][scol + 8] = kr1;
        *(int4*)&Vs[srow][scol]     = vr0;
        *(int4*)&Vs[srow][scol + 8] = vr1;
        __syncthreads();

        if (kt < 15) {
            kr0 = *(const int4*)(kp + (kt + 1) * 4096 + srow * 64 + scol);
            kr1 = *(const int4*)(kp + (kt + 1) * 4096 + srow * 64 + scol + 8);
            vr0 = *(const int4*)(vp + (size_t)srow * 8192 + (kt + 1) * 64 + scol);
            vr1 = *(const int4*)(vp + (size_t)srow * 8192 + (kt + 1) * 64 + scol + 8);
        }

        // S^T = K x Q^T (keys permuted per tile)
        f32x4 Sacc[2][4];
#pragma unroll
        for (int qg = 0; qg < 2; ++qg)
#pragma unroll
            for (int tk = 0; tk < 4; ++tk) Sacc[qg][tk] = zero4;
#pragma unroll
        for (int ks = 0; ks < 2; ++ks) {
#pragma unroll
            for (int tk = 0; tk < 4; ++tk) {
                const bf16x8 kf = *(const bf16x8*)&Ks[tk * 16 + l15][ks * 32 + quad * 8];
                Sacc[0][tk] = __builtin_amdgcn_mfma_f32_16x16x32_bf16(kf, qf[0][ks], Sacc[0][tk], 0, 0, 0);
                Sacc[1][tk] = __builtin_amdgcn_mfma_f32_16x16x32_bf16(kf, qf[1][ks], Sacc[1][tk], 0, 0, 0);
            }
        }

        // P = exp2(S'), truncation-packed into K=32 A-fragments
        union { bf16x8 v; unsigned u[4]; } pf[2][2];
#pragma unroll
        for (int qg = 0; qg < 2; ++qg)
#pragma unroll
            for (int tk = 0; tk < 4; ++tk) {
                const float p0 = EXP2(Sacc[qg][tk][0]);
                const float p1 = EXP2(Sacc[qg][tk][1]);
                const float p2 = EXP2(Sacc[qg][tk][2]);
                const float p3 = EXP2(Sacc[qg][tk][3]);
                const int g = tk >> 1, hf = (tk & 1) * 2;
                pf[qg][g].u[hf + 0] = packtrunc(p0, p1);
                pf[qg][g].u[hf + 1] = packtrunc(p2, p3);
            }

        // Z += P * t_v (full-rate K=32), L += P * ones
#pragma unroll
        for (int g = 0; g < 2; ++g) {
#pragma unroll
            for (int tn = 0; tn < 4; ++tn) {
                const bf16x8 vf = *(const bf16x8*)&Vs[tn * 16 + l15][g * 32 + quad * 8];
                o_acc[0][tn] = __builtin_amdgcn_mfma_f32_16x16x32_bf16(pf[0][g].v, vf, o_acc[0][tn], 0, 0, 0);
                o_acc[1][tn] = __builtin_amdgcn_mfma_f32_16x16x32_bf16(pf[1][g].v, vf, o_acc[1][tn], 0, 0, 0);
            }
            Lacc[0] = __builtin_amdgcn_mfma_f32_16x16x32_bf16(pf[0][g].v, vone, Lacc[0], 0, 0, 0);
            Lacc[1] = __builtin_amdgcn_mfma_f32_16x16x32_bf16(pf[1][g].v, vone, Lacc[1], 0, 0, 0);
        }
    }

    // epilogue: Z[token][h*64 + r'], r' = tn*16+l15; L at lane quad*16, reg r
#pragma unroll
    for (int qg = 0; qg < 2; ++qg) {
#pragma unroll
        for (int r = 0; r < 4; ++r) {
            const float Lv = __shfl(Lacc[qg][r], quad << 4, 64);
            const float inv = 1.0f / Lv;
            const int token = qt * 128 + wv * 32 + qg * 16 + quad * 4 + r;
#pragma unroll
            for (int tn = 0; tn < 4; ++tn) {
                const int col = h * 64 + tn * 16 + l15;
                Z[(size_t)(b * 1024 + token) * 768 + col] = f2b(o_acc[qg][tn][r] * inv);
            }
        }
    }
}

// ---------------------------------------------------------------------------
// Kernel 5: out = Zcat @ Dcat^T + bias, fp32 out. 128x64 tiles, grid (12,64).
// ---------------------------------------------------------------------------
__global__ __launch_bounds__(256, 3) void gemm_out(
    const u16* __restrict__ A, const u16* __restrict__ Bt,
    float* __restrict__ C, const float* __restrict__ bias)
{
    __shared__ u16 As[128 * 32];
    __shared__ u16 Bs[64 * 32];

    const int tid  = threadIdx.x;
    const int lane = tid & 63, wv = tid >> 6;
    const int l15  = lane & 15, quad = lane >> 4;
    const int rowBase = blockIdx.y * 128;
    const int colBase = blockIdx.x * 64;

    const int srowA = wv * 32 + (lane >> 2);
    const int srowB = wv * 16 + (lane >> 2);
    const int scol  = (lane & 3) * 8;
    const u16* aSrc = A  + (size_t)(rowBase + srowA) * 768 + scol;
    const u16* bSrc = Bt + (size_t)(colBase + srowB) * 768 + scol;
    u16* aDst = As + wv * 1024;
    u16* bDst = Bs + wv * 512;

    const f32x4 zero4 = {0.f, 0.f, 0.f, 0.f};
    f32x4 acc[2][4];
#pragma unroll
    for (int tm = 0; tm < 2; ++tm)
#pragma unroll
        for (int tn = 0; tn < 4; ++tn) acc[tm][tn] = zero4;

    for (int kk = 0; kk < 768; kk += 32) {
        __syncthreads();
        g2l16(aSrc + kk,            aDst);
        g2l16(aSrc + kk + 16 * 768, aDst + 512);
        g2l16(bSrc + kk,            bDst);
        __syncthreads();

        bf16x8 af[2], bfm[4];
#pragma unroll
        for (int t = 0; t < 2; ++t)
            af[t]  = *(const bf16x8*)(As + (wv * 32 + t * 16 + l15) * 32 + quad * 8);
#pragma unroll
        for (int t = 0; t < 4; ++t)
            bfm[t] = *(const bf16x8*)(Bs + (t * 16 + l15) * 32 + quad * 8);
#pragma unroll
        for (int tm = 0; tm < 2; ++tm)
#pragma unroll
            for (int tn = 0; tn < 4; ++tn)
                acc[tm][tn] = __builtin_amdgcn_mfma_f32_16x16x32_bf16(
                    af[tm], bfm[tn], acc[tm][tn], 0, 0, 0);
    }

#pragma unroll
    for (int tm = 0; tm < 2; ++tm) {
        const int grow = rowBase + wv * 32 + tm * 16 + quad * 4;
#pragma unroll
        for (int tn = 0; tn < 4; ++tn) {
            const int gcol = colBase + tn * 16 + l15;
            const float bv = bias[gcol];
#pragma unroll
            for (int r = 0; r < 4; ++r)
                C[(size_t)(grow + r) * 768 + gcol] = acc[tm][tn][r] + bv;
        }
    }
}

// ---------------------------------------------------------------------------
extern "C" void kernel_launch(void* const* d_in, const int* in_sizes, int n_in,
                              void* d_out, int out_size, void* d_ws, size_t ws_size,
                              hipStream_t stream)
{
    const float* x      = (const float*)d_in[0];
    const float* Wq0    = (const float*)d_in[1];
    const float* Wq1    = (const float*)d_in[2];
    const float* Wq2    = (const float*)d_in[3];
    const float* Wk0    = (const float*)d_in[4];
    const float* Wk1    = (const float*)d_in[5];
    const float* Wk2    = (const float*)d_in[6];
    const float* Wv0    = (const float*)d_in[7];
    const float* Wv1    = (const float*)d_in[8];
    const float* Wv2    = (const float*)d_in[9];
    const float* proj_w = (const float*)d_in[10];
    const float* proj_b = (const float*)d_in[11];
    float* outp = (float*)d_out;

    char* ws = (char*)d_ws;
    u16* T    = (u16*)ws;                       // 8192*128*2 = 2,097,152 B
    u16* tvt  = (u16*)(ws + 2097152);           // 64*8192*2  = 1,048,576 B
    u16* G    = (u16*)(ws + 3145728);           //   294,912 B
    u16* W0b  = (u16*)(ws + 3440640);           //   294,912 B
    u16* Dcat = (u16*)(ws + 3735552);           // 1,179,648 B
    u16* Zcat = (u16*)(ws + 4915200);           // 12,582,912 B
    u16* qk   = (u16*)(ws + 17498112);          // 25,165,824 B; end = 42,663,936 B

    build_prep<<<1440, 256, 0, stream>>>(Wq0, Wq1, Wq2, Wk0, Wk1, Wk2, Wv0, Wv1, Wv2,
                                         proj_w, G, W0b, Dcat);
    gemm_t<<<dim3(3, 128), 256, 0, stream>>>(x, G, T, tvt);
    gemm_expand<<<dim3(12, 64), 256, 0, stream>>>(T, W0b, qk);
    flash_attn6<<<dim3(8, 96), 256, 0, stream>>>(qk, tvt, Zcat);
    gemm_out<<<dim3(12, 64), 256, 0, stream>>>(Zcat, Dcat, outp, proj_b);
}